// Round 2
// baseline (342.888 us; speedup 1.0000x reference)
//
#include <hip/hip_runtime.h>

// out[b,n,m] = sum_d x1[b,n,d] * x2[b,m,d] + const
// B=4, N=M=4096, D=32, fp32.
//
// R1 analysis: R0 (64x64 tile, 4x4 micro) was LDS-pipe bound:
//   64 ds_read_b128/wave/tile * 12cyc * 16384 insts/CU = 82us ~= measured 78us.
// Fix: 8x8 microtile on 128x128 tile -> LDS bytes/FLOP halved -> LDS pipe ~41us,
// at parity with the 38us HBM-write floor (268MB @ ~7TB/s measured via memsets).

constexpr int Bv = 4;
constexpr int Nv = 4096;
constexpr int Mv = 4096;
constexpr int Dv = 32;
constexpr int TM = 128;       // tile rows (n)
constexpr int TN = 128;       // tile cols (m)
constexpr int LROW = 132;     // LDS words per d-row: 128 + 4 pad (16B-aligned rows)

__global__ __launch_bounds__(256, 4)
void pairwise_dot_bias_kernel(const float* __restrict__ x1,
                              const float* __restrict__ x2,
                              const float* __restrict__ cbias,
                              float* __restrict__ out) {
    // d-major LDS: a_s[d][row], b_s[d][col] -> per-d reads are row-contiguous b128
    __shared__ float a_s[Dv][LROW];
    __shared__ float b_s[Dv][LROW];

    const int b  = blockIdx.z;
    const int n0 = blockIdx.y * TM;
    const int m0 = blockIdx.x * TN;
    const int t  = threadIdx.x;   // 0..255

    const float* x1b = x1 + (size_t)b * Nv * Dv + (size_t)n0 * Dv;
    const float* x2b = x2 + (size_t)b * Mv * Dv + (size_t)m0 * Dv;

    // ---- stage: fully-coalesced float4 global loads, transpose to d-major ----
    // 128 rows x 32 floats per matrix = 4096 words; 256 threads x 4 passes x float4.
    #pragma unroll
    for (int p = 0; p < 4; ++p) {
        const int flat = p * 1024 + t * 4;   // word offset in the 128x32 tile
        const int row  = flat >> 5;          // 0..127
        const int col  = flat & 31;          // 0,4,..,28
        const float4 av = *reinterpret_cast<const float4*>(x1b + flat);
        const float4 bv = *reinterpret_cast<const float4*>(x2b + flat);
        a_s[col + 0][row] = av.x;
        a_s[col + 1][row] = av.y;
        a_s[col + 2][row] = av.z;
        a_s[col + 3][row] = av.w;
        b_s[col + 0][row] = bv.x;
        b_s[col + 1][row] = bv.y;
        b_s[col + 2][row] = bv.z;
        b_s[col + 3][row] = bv.w;
    }
    __syncthreads();

    // ---- compute: 8x8 micro-tile per thread ----
    const int tx = t & 15;        // col group: cols m0 + 8*tx .. +7
    const int ty = t >> 4;        // row group: rows n0 + 8*ty .. +7

    float acc[8][8];
    #pragma unroll
    for (int i = 0; i < 8; ++i)
        #pragma unroll
        for (int j = 0; j < 8; ++j)
            acc[i][j] = 0.0f;

    #pragma unroll
    for (int d = 0; d < Dv; ++d) {
        const float4 a0 = *reinterpret_cast<const float4*>(&a_s[d][ty * 8]);
        const float4 a1 = *reinterpret_cast<const float4*>(&a_s[d][ty * 8 + 4]);
        const float4 b0 = *reinterpret_cast<const float4*>(&b_s[d][tx * 8]);
        const float4 b1 = *reinterpret_cast<const float4*>(&b_s[d][tx * 8 + 4]);
        const float av[8] = {a0.x, a0.y, a0.z, a0.w, a1.x, a1.y, a1.z, a1.w};
        const float bw[8] = {b0.x, b0.y, b0.z, b0.w, b1.x, b1.y, b1.z, b1.w};
        #pragma unroll
        for (int i = 0; i < 8; ++i)
            #pragma unroll
            for (int j = 0; j < 8; ++j)
                acc[i][j] = fmaf(av[i], bw[j], acc[i][j]);
    }

    // ---- store: 8 rows x 2 coalesced float4 per thread ----
    const float cb = cbias[0];
    float* outb = out + (size_t)b * Nv * Mv;
    #pragma unroll
    for (int i = 0; i < 8; ++i) {
        float* orow = outb + (size_t)(n0 + ty * 8 + i) * Mv + (m0 + tx * 8);
        float4 v0, v1;
        v0.x = acc[i][0] + cb; v0.y = acc[i][1] + cb;
        v0.z = acc[i][2] + cb; v0.w = acc[i][3] + cb;
        v1.x = acc[i][4] + cb; v1.y = acc[i][5] + cb;
        v1.z = acc[i][6] + cb; v1.w = acc[i][7] + cb;
        *reinterpret_cast<float4*>(orow)     = v0;
        *reinterpret_cast<float4*>(orow + 4) = v1;
    }
}

extern "C" void kernel_launch(void* const* d_in, const int* in_sizes, int n_in,
                              void* d_out, int out_size, void* d_ws, size_t ws_size,
                              hipStream_t stream) {
    const float* x1 = (const float*)d_in[0];   // [B,N,D]
    const float* x2 = (const float*)d_in[1];   // [B,M,D]
    const float* cb = (const float*)d_in[2];   // [1]
    float* out = (float*)d_out;                // [B,N,M]

    dim3 grid(Mv / TN, Nv / TM, Bv);           // 32 x 32 x 4 blocks
    pairwise_dot_bias_kernel<<<grid, 256, 0, stream>>>(x1, x2, cb, out);
}

// Round 3
// 80.352 us; speedup vs baseline: 4.2673x; 4.2673x over previous
//
#include <hip/hip_runtime.h>

// out[b,n,m] = sum_d x1[b,n,d] * x2[b,m,d] + const
// B=4, N=M=4096, D=32, fp32.
//
// R2: R1 regressed 78->343us because __launch_bounds__(256,4) capped VGPRs at
// 128 and the compiler spilled the 64-reg accumulator to scratch (FETCH 494MB,
// WRITE 1.13GB of spill traffic). Fix: (256,2) -> 256-VGPR cap, no spill.
// Structure unchanged: 128x128 tile, 8x8 microtile, d-major LDS, single
// barrier (D=32 fits in one staging phase).

constexpr int Bv = 4;
constexpr int Nv = 4096;
constexpr int Mv = 4096;
constexpr int Dv = 32;
constexpr int TM = 128;       // tile rows (n)
constexpr int TN = 128;       // tile cols (m)
constexpr int LROW = 132;     // LDS words per d-row: 128 + 4 pad (keeps 16B alignment)

__global__ __launch_bounds__(256, 2)   // 256-VGPR cap: acc(64)+operands fits, NO spill
void pairwise_dot_bias_kernel(const float* __restrict__ x1,
                              const float* __restrict__ x2,
                              const float* __restrict__ cbias,
                              float* __restrict__ out) {
    // d-major LDS: a_s[d][row], b_s[d][col] -> per-d reads are row-contiguous b128
    __shared__ float a_s[Dv][LROW];
    __shared__ float b_s[Dv][LROW];

    const int b  = blockIdx.z;
    const int n0 = blockIdx.y * TM;
    const int m0 = blockIdx.x * TN;
    const int t  = threadIdx.x;   // 0..255

    const float* x1b = x1 + (size_t)b * Nv * Dv + (size_t)n0 * Dv;
    const float* x2b = x2 + (size_t)b * Mv * Dv + (size_t)m0 * Dv;

    // ---- stage: fully-coalesced float4 global loads, transpose to d-major ----
    #pragma unroll
    for (int p = 0; p < 4; ++p) {
        const int flat = p * 1024 + t * 4;   // word offset in the 128x32 tile
        const int row  = flat >> 5;          // 0..127
        const int col  = flat & 31;          // 0,4,..,28
        const float4 av = *reinterpret_cast<const float4*>(x1b + flat);
        const float4 bv = *reinterpret_cast<const float4*>(x2b + flat);
        a_s[col + 0][row] = av.x;
        a_s[col + 1][row] = av.y;
        a_s[col + 2][row] = av.z;
        a_s[col + 3][row] = av.w;
        b_s[col + 0][row] = bv.x;
        b_s[col + 1][row] = bv.y;
        b_s[col + 2][row] = bv.z;
        b_s[col + 3][row] = bv.w;
    }
    __syncthreads();

    // ---- compute: 8x8 micro-tile per thread ----
    const int tx = t & 15;        // col group: cols m0 + 8*tx .. +7
    const int ty = t >> 4;        // row group: rows n0 + 8*ty .. +7

    float acc[8][8];
    #pragma unroll
    for (int i = 0; i < 8; ++i)
        #pragma unroll
        for (int j = 0; j < 8; ++j)
            acc[i][j] = 0.0f;

    #pragma unroll
    for (int d = 0; d < Dv; ++d) {
        const float4 a0 = *reinterpret_cast<const float4*>(&a_s[d][ty * 8]);
        const float4 a1 = *reinterpret_cast<const float4*>(&a_s[d][ty * 8 + 4]);
        const float4 b0 = *reinterpret_cast<const float4*>(&b_s[d][tx * 8]);
        const float4 b1 = *reinterpret_cast<const float4*>(&b_s[d][tx * 8 + 4]);
        const float av[8] = {a0.x, a0.y, a0.z, a0.w, a1.x, a1.y, a1.z, a1.w};
        const float bw[8] = {b0.x, b0.y, b0.z, b0.w, b1.x, b1.y, b1.z, b1.w};
        #pragma unroll
        for (int i = 0; i < 8; ++i)
            #pragma unroll
            for (int j = 0; j < 8; ++j)
                acc[i][j] = fmaf(av[i], bw[j], acc[i][j]);
    }

    // ---- store: 8 rows x 2 coalesced float4 per thread ----
    const float cb = cbias[0];
    float* outb = out + (size_t)b * Nv * Mv;
    #pragma unroll
    for (int i = 0; i < 8; ++i) {
        float* orow = outb + (size_t)(n0 + ty * 8 + i) * Mv + (m0 + tx * 8);
        float4 v0, v1;
        v0.x = acc[i][0] + cb; v0.y = acc[i][1] + cb;
        v0.z = acc[i][2] + cb; v0.w = acc[i][3] + cb;
        v1.x = acc[i][4] + cb; v1.y = acc[i][5] + cb;
        v1.z = acc[i][6] + cb; v1.w = acc[i][7] + cb;
        *reinterpret_cast<float4*>(orow)     = v0;
        *reinterpret_cast<float4*>(orow + 4) = v1;
    }
}

extern "C" void kernel_launch(void* const* d_in, const int* in_sizes, int n_in,
                              void* d_out, int out_size, void* d_ws, size_t ws_size,
                              hipStream_t stream) {
    const float* x1 = (const float*)d_in[0];   // [B,N,D]
    const float* x2 = (const float*)d_in[1];   // [B,M,D]
    const float* cb = (const float*)d_in[2];   // [1]
    float* out = (float*)d_out;                // [B,N,M]

    dim3 grid(Mv / TN, Nv / TM, Bv);           // 32 x 32 x 4 blocks
    pairwise_dot_bias_kernel<<<grid, 256, 0, stream>>>(x1, x2, cb, out);
}

// Round 4
// 66.754 us; speedup vs baseline: 5.1366x; 1.2037x over previous
//
#include <hip/hip_runtime.h>

// out[b,n,m] = sum_d x1[b,n,d] * x2[b,m,d] + const
// B=4, N=M=4096, D=32, fp32.
//
// R3: R2 (80us) was LDS-pipe bound with a 4-way bank conflict on the b-read
// (16 lanes at 32B stride -> 4 addrs/bank-quad) and half-line scattered
// stores. Fix: column split h*64 + tx*4 (b-reads 16B-strided -> 2-way free;
// stores contiguous 256B/row/inst) + 8x16 microtile on a 128x256 tile so the
// LDS pipe (~31us) drops below the 38us HBM-write floor.

constexpr int Bv = 4;
constexpr int Nv = 4096;
constexpr int Mv = 4096;
constexpr int Dv = 32;
constexpr int TM = 128;        // tile rows (n)
constexpr int TN = 256;        // tile cols (m)
constexpr int LRA = 132;       // a_s row stride (words): 128+4, 16B-aligned
constexpr int LRB = 260;       // b_s row stride (words): 256+4, 16B-aligned

__global__ __launch_bounds__(256, 2)   // 256-VGPR cap: ~200 needed, no spill
void pairwise_dot_bias_kernel(const float* __restrict__ x1,
                              const float* __restrict__ x2,
                              const float* __restrict__ cbias,
                              float* __restrict__ out) {
    __shared__ float a_s[Dv][LRA];   // d-major: a_s[d][row]
    __shared__ float b_s[Dv][LRB];   // d-major: b_s[d][col]

    const int b  = blockIdx.z;
    const int n0 = blockIdx.y * TM;
    const int m0 = blockIdx.x * TN;
    const int t  = threadIdx.x;      // 0..255

    const float* x1b = x1 + (size_t)b * Nv * Dv + (size_t)n0 * Dv;
    const float* x2b = x2 + (size_t)b * Mv * Dv + (size_t)m0 * Dv;

    // ---- stage A: 128 rows x 32 d, coalesced float4, transpose to d-major ----
    #pragma unroll
    for (int p = 0; p < 4; ++p) {
        const int flat = p * 1024 + t * 4;
        const int row  = flat >> 5;
        const int col  = flat & 31;
        const float4 av = *reinterpret_cast<const float4*>(x1b + flat);
        a_s[col + 0][row] = av.x;
        a_s[col + 1][row] = av.y;
        a_s[col + 2][row] = av.z;
        a_s[col + 3][row] = av.w;
    }
    // ---- stage B: 256 rows x 32 d ----
    #pragma unroll
    for (int p = 0; p < 8; ++p) {
        const int flat = p * 1024 + t * 4;
        const int row  = flat >> 5;
        const int col  = flat & 31;
        const float4 bv = *reinterpret_cast<const float4*>(x2b + flat);
        b_s[col + 0][row] = bv.x;
        b_s[col + 1][row] = bv.y;
        b_s[col + 2][row] = bv.z;
        b_s[col + 3][row] = bv.w;
    }
    __syncthreads();

    // ---- compute: 8 rows x 16 cols per thread ----
    // rows: n0 + ty*8 + i (i<8); cols: m0 + h*64 + tx*4 + j (h<4, j<4)
    const int tx = t & 15;
    const int ty = t >> 4;

    float acc[8][16];
    #pragma unroll
    for (int i = 0; i < 8; ++i)
        #pragma unroll
        for (int j = 0; j < 16; ++j)
            acc[i][j] = 0.0f;

    #pragma unroll 2
    for (int d = 0; d < Dv; ++d) {
        // a: 2 b128, address uniform over tx -> 16-lane broadcast (free)
        const float4 a0 = *reinterpret_cast<const float4*>(&a_s[d][ty * 8]);
        const float4 a1 = *reinterpret_cast<const float4*>(&a_s[d][ty * 8 + 4]);
        // b: 4 b128 at 16B lane stride -> 2-way bank aliasing (free)
        const float4 b0 = *reinterpret_cast<const float4*>(&b_s[d][tx * 4]);
        const float4 b1 = *reinterpret_cast<const float4*>(&b_s[d][64 + tx * 4]);
        const float4 b2 = *reinterpret_cast<const float4*>(&b_s[d][128 + tx * 4]);
        const float4 b3 = *reinterpret_cast<const float4*>(&b_s[d][192 + tx * 4]);
        const float av[8]  = {a0.x, a0.y, a0.z, a0.w, a1.x, a1.y, a1.z, a1.w};
        const float bw[16] = {b0.x, b0.y, b0.z, b0.w, b1.x, b1.y, b1.z, b1.w,
                              b2.x, b2.y, b2.z, b2.w, b3.x, b3.y, b3.z, b3.w};
        #pragma unroll
        for (int i = 0; i < 8; ++i)
            #pragma unroll
            for (int j = 0; j < 16; ++j)
                acc[i][j] = fmaf(av[i], bw[j], acc[i][j]);
    }

    // ---- store: 8 rows x 4 float4; per inst: 4 rows x contiguous 256B ----
    const float cb = cbias[0];
    float* outb = out + (size_t)b * Nv * Mv;
    #pragma unroll
    for (int i = 0; i < 8; ++i) {
        float* orow = outb + (size_t)(n0 + ty * 8 + i) * Mv + m0;
        #pragma unroll
        for (int h = 0; h < 4; ++h) {
            float4 v;
            v.x = acc[i][h * 4 + 0] + cb;
            v.y = acc[i][h * 4 + 1] + cb;
            v.z = acc[i][h * 4 + 2] + cb;
            v.w = acc[i][h * 4 + 3] + cb;
            *reinterpret_cast<float4*>(orow + h * 64 + tx * 4) = v;
        }
    }
}

extern "C" void kernel_launch(void* const* d_in, const int* in_sizes, int n_in,
                              void* d_out, int out_size, void* d_ws, size_t ws_size,
                              hipStream_t stream) {
    const float* x1 = (const float*)d_in[0];   // [B,N,D]
    const float* x2 = (const float*)d_in[1];   // [B,M,D]
    const float* cb = (const float*)d_in[2];   // [1]
    float* out = (float*)d_out;                // [B,N,M]

    dim3 grid(Mv / TN, Nv / TM, Bv);           // 16 x 32 x 4 blocks
    pairwise_dot_bias_kernel<<<grid, 256, 0, stream>>>(x1, x2, cb, out);
}